// Round 6
// baseline (348.010 us; speedup 1.0000x reference)
//
#include <hip/hip_runtime.h>
#include <hip/hip_bf16.h>
#include <hip/hip_fp16.h>

#define N_NODES 100000
#define N_EDGES 1600000
#define IN_DIM 256
#define HIDDEN 128
#define NCLS 40
#define NCLS_PAD 48      // padded to 3 MFMA n-tiles

#define N_BUCKETS 256
#define NPB 391          // nodes per bucket = ceil(100000/256)
#define BCAP 8192        // bucket capacity (mean 6256, +24 sigma)
#define EPT 16           // edges per thread in bin phase
#define BIN_WG 4096      // edges per workgroup (256*16)
#define BIN_BLOCKS 391   // ceil(N_EDGES / BIN_WG)
#define GEMM1_BLOCKS 782 // ceil(N_NODES / 128)

typedef __attribute__((ext_vector_type(8))) _Float16 half8;
typedef __attribute__((ext_vector_type(4))) _Float16 half4f;
typedef __attribute__((ext_vector_type(4))) float floatx4;

// ---------------- k_prep: W1T / W2T fp16 transposes + bfill zero ----------------

__global__ __launch_bounds__(256) void k_prep(const float* __restrict__ W1, __half* __restrict__ W1T,
                                              const float* __restrict__ W2, __half* __restrict__ W2T,
                                              int* __restrict__ bfill) {
    const int t = threadIdx.x;
    if (blockIdx.x < 128) {              // W1T: [n][k] fp16, 128 x 256
        int i = blockIdx.x * 256 + t;
        int k = i >> 7, n = i & 127;
        W1T[n * IN_DIM + k] = __float2half_rn(W1[i]);
    } else if (blockIdx.x == 128) {      // W2T: [n][k] fp16, 48 x 128, zero-pad n>=40
        for (int i = t; i < NCLS_PAD * HIDDEN; i += 256) {
            int n = i >> 7, k = i & 127;
            W2T[n * HIDDEN + k] = (n < NCLS) ? __float2half_rn(W2[k * NCLS + n]) : __float2half_rn(0.f);
        }
    } else {
        bfill[t] = 0;
    }
}

// ---------------- k_binmm: [0,391) LDS-staged edge binning  ∥  [391,1173) GEMM1 (unscaled) ----------------
// Bin phase: round-3 proven config (256 buckets, bid[] array, 128B/bucket scatter
// chunks -> no partial-line write amplification). GEMM phase: A AND B prefetched into
// registers for kc+1 right after the post-store barrier, so both HBM(A) and L2(B)
// latency hide under the MFMA block.

__global__ __launch_bounds__(256) void k_binmm(const int* __restrict__ src, const int* __restrict__ dst,
                                               int* __restrict__ bfill,
                                               unsigned long long* __restrict__ bpair,
                                               const float* __restrict__ X,
                                               const __half* __restrict__ W1T,
                                               __half* __restrict__ H1s) {
    __shared__ __align__(16) char smraw[39936];   // union: bin(39936) / gemm1(36864)
    const int t = threadIdx.x;

    if (blockIdx.x < BIN_BLOCKS) {
        // ---- bin phase ----
        int* hist   = (int*)smraw;                               // 256
        int* bstart = hist + 256;                                // 256
        int* gbase  = bstart + 256;                              // 256
        unsigned long long* stage = (unsigned long long*)(smraw + 3072);   // 4096 (32 KB)
        unsigned char* bid = (unsigned char*)(smraw + 3072 + 32768);       // 4096
        hist[t] = 0;
        __syncthreads();
        const long e0 = (long)blockIdx.x * BIN_WG;
        const int n_valid = (int)min((long)BIN_WG, (long)N_EDGES - e0);
        int msrc[EPT], mdst[EPT], moff[EPT];
        #pragma unroll
        for (int i = 0; i < EPT; i++) {
            long e = e0 + t + i * 256;
            if (e < N_EDGES) {
                msrc[i] = src[e];
                mdst[i] = dst[e];
                moff[i] = atomicAdd(&hist[mdst[i] / NPB], 1);
            } else {
                mdst[i] = -1;
            }
        }
        __syncthreads();
        if (t < 64) {   // wave 0: exclusive scan of hist[256]
            int carry = 0;
            #pragma unroll
            for (int c = 0; c < 4; c++) {
                int idx = c * 64 + t;
                int hv = hist[idx];
                int s = hv;
                #pragma unroll
                for (int d2 = 1; d2 < 64; d2 <<= 1) {
                    int u = __shfl_up(s, d2, 64);
                    if (t >= d2) s += u;
                }
                bstart[idx] = carry + (s - hv);
                carry += __shfl(s, 63, 64);
            }
        }
        __syncthreads();
        int h = hist[t];
        gbase[t] = (h > 0) ? atomicAdd(&bfill[t], h) : 0;
        #pragma unroll
        for (int i = 0; i < EPT; i++) {
            if (mdst[i] >= 0) {
                int b = mdst[i] / NPB;
                int pos = bstart[b] + moff[i];
                stage[pos] = ((unsigned long long)(unsigned)mdst[i] << 32) | (unsigned)msrc[i];
                bid[pos] = (unsigned char)b;
            }
        }
        __syncthreads();
        for (int i = t; i < n_valid; i += 256) {
            int b = bid[i];
            int dest = gbase[b] + (i - bstart[b]);
            bpair[(long)b * BCAP + dest] = stage[i];
        }
        return;
    }

    // ---- gemm1 phase (128x128 tile, MFMA f16, unscaled output) ----
    _Float16 (*Asm)[72] = (_Float16(*)[72])smraw;
    _Float16 (*Bsm)[72] = (_Float16(*)[72])(smraw + 128 * 72 * 2);
    const int wave = t >> 6;
    const int lane = t & 63;
    const int m16  = lane & 15;
    const int kq   = lane >> 4;
    const int row0 = (blockIdx.x - BIN_BLOCKS) * 128;

    floatx4 acc[2][8];
    #pragma unroll
    for (int mt = 0; mt < 2; mt++)
        #pragma unroll
        for (int i = 0; i < 8; i++) acc[mt][i] = (floatx4)0.f;

    float4 ar[4][2];   // A-tile prefetch registers (32B/thread)
    float4 br[4];      // B-tile prefetch registers (16B/thread)
    auto loadA = [&](int kcL) {
        #pragma unroll
        for (int it = 0; it < 4; it++) {
            int u = t + it * 256;
            int r = u >> 3, j = u & 7;
            int gr = row0 + r;
            if (gr < N_NODES) {
                const float* p = &X[(long)gr * IN_DIM + kcL * 64 + j * 8];
                ar[it][0] = *(const float4*)p;
                ar[it][1] = *(const float4*)(p + 4);
            } else {
                ar[it][0] = make_float4(0.f, 0.f, 0.f, 0.f);
                ar[it][1] = make_float4(0.f, 0.f, 0.f, 0.f);
            }
        }
    };
    auto loadB = [&](int kcL) {
        #pragma unroll
        for (int it = 0; it < 4; it++) {
            int u = t + it * 256;
            int n = u >> 3, j = u & 7;
            br[it] = *(const float4*)&W1T[n * IN_DIM + kcL * 64 + j * 8];
        }
    };

    loadA(0); loadB(0);
    for (int kc = 0; kc < 4; kc++) {
        // store prefetched A (cvt fp32->fp16) and B
        #pragma unroll
        for (int it = 0; it < 4; it++) {
            int u = t + it * 256;
            int r = u >> 3, j = u & 7;
            half8 hh;
            hh[0] = (_Float16)ar[it][0].x; hh[1] = (_Float16)ar[it][0].y;
            hh[2] = (_Float16)ar[it][0].z; hh[3] = (_Float16)ar[it][0].w;
            hh[4] = (_Float16)ar[it][1].x; hh[5] = (_Float16)ar[it][1].y;
            hh[6] = (_Float16)ar[it][1].z; hh[7] = (_Float16)ar[it][1].w;
            *(half8*)&Asm[r][j * 8] = hh;
        }
        #pragma unroll
        for (int it = 0; it < 4; it++) {
            int u = t + it * 256;
            int n = u >> 3, j = u & 7;
            *(float4*)&Bsm[n][j * 8] = br[it];
        }
        __syncthreads();
        if (kc < 3) { loadA(kc + 1); loadB(kc + 1); }   // latency hides under MFMA
        #pragma unroll
        for (int ks = 0; ks < 2; ks++) {
            half8 a0 = *(const half8*)&Asm[wave * 32 + m16][ks * 32 + kq * 8];
            half8 a1 = *(const half8*)&Asm[wave * 32 + 16 + m16][ks * 32 + kq * 8];
            #pragma unroll
            for (int nt = 0; nt < 8; nt++) {
                half8 b = *(const half8*)&Bsm[nt * 16 + m16][ks * 32 + kq * 8];
                acc[0][nt] = __builtin_amdgcn_mfma_f32_16x16x32_f16(a0, b, acc[0][nt], 0, 0, 0);
                acc[1][nt] = __builtin_amdgcn_mfma_f32_16x16x32_f16(a1, b, acc[1][nt], 0, 0, 0);
            }
        }
        __syncthreads();
    }
    #pragma unroll
    for (int mt = 0; mt < 2; mt++) {
        const int gr0 = row0 + wave * 32 + mt * 16 + kq * 4;
        #pragma unroll
        for (int nt = 0; nt < 8; nt++) {
            int c = nt * 16 + m16;
            #pragma unroll
            for (int r = 0; r < 4; r++) {
                if (gr0 + r < N_NODES)
                    H1s[(long)(gr0 + r) * HIDDEN + c] = __float2half_rn(acc[mt][nt][r]);
            }
        }
    }
}

// ---------------- k_build: histogram -> prefix -> row_ptr/dinv -> scatter ----------------
// (no H1 scaling: dinv[src] folds into k_agg1g2 via SCALAR loads)

__global__ __launch_bounds__(256) void k_build(const int* __restrict__ bfill,
                                               const unsigned long long* __restrict__ bpair,
                                               int* __restrict__ row_ptr, float* __restrict__ dinv,
                                               int* __restrict__ col) {
    __shared__ int h[NPB];
    __shared__ int pfx[NPB];
    __shared__ int sred[4];
    const int b  = blockIdx.x;
    const int nb = b * NPB;
    const int nn = min(NPB, N_NODES - nb);
    const int t  = threadIdx.x;
    int v = (t < b) ? bfill[t] : 0;
    #pragma unroll
    for (int dl = 32; dl > 0; dl >>= 1) v += __shfl_down(v, dl, 64);
    if ((t & 63) == 0) sred[t >> 6] = v;
    for (int i = t; i < NPB; i += 256) h[i] = 0;
    __syncthreads();
    const int base_b = sred[0] + sred[1] + sred[2] + sred[3];
    const int n = bfill[b];
    for (int i = t; i < n; i += 256) {
        int dd = (int)(bpair[(long)b * BCAP + i] >> 32);
        atomicAdd(&h[dd - nb], 1);
    }
    __syncthreads();
    if (t < 64) {   // wave 0: exclusive scan of degrees
        int carry = 0;
        #pragma unroll
        for (int c = 0; c < (NPB + 63) / 64; c++) {
            int idx = c * 64 + t;
            int hv = (idx < nn) ? h[idx] : 0;
            int s = hv;
            #pragma unroll
            for (int d2 = 1; d2 < 64; d2 <<= 1) {
                int u = __shfl_up(s, d2, 64);
                if (t >= d2) s += u;
            }
            if (idx < nn) {
                int ex = base_b + carry + (s - hv);
                pfx[idx] = ex;
                row_ptr[nb + idx] = ex;
                dinv[nb + idx] = rsqrtf((float)(hv + 1));   // +1 self-loop
            }
            carry += __shfl(s, 63, 64);
        }
    }
    __syncthreads();
    for (int i = t; i < nn; i += 256) h[i] = 0;   // reuse as fill counters
    __syncthreads();
    for (int i = t; i < n; i += 256) {
        unsigned long long p = bpair[(long)b * BCAP + i];
        int dd = (int)(p >> 32);
        int ss = (int)(p & 0xFFFFFFFFu);
        int pos = pfx[dd - nb] + atomicAdd(&h[dd - nb], 1);
        col[pos] = ss;
    }
    if (b == 0 && t == 0) row_ptr[N_NODES] = N_EDGES;
}

// ---------------- k_agg1g2: Agg1 (+bias+ReLU, pre-scale) + MFMA GEMM2 -> H2s fp16 ----------------
// Block = 16 nodes, each wave serially aggregates 4 nodes with a full-row gather per
// edge (64 lanes x half2 = 256B). e0/e1 forced to SGPR via readfirstlane so col[e..]
// are SGPR scalar loads; therefore dinv[col[e]] are ALSO uniform-address scalar loads
// (SMEM pipe, overlapped with the VMEM gathers) and the sym-norm scale folds into the
// accumulate as fmac-with-SGPR — no separate H1-scale pass anywhere. 8 gathers in flight.

__global__ __launch_bounds__(256) void k_agg1g2(const __half* __restrict__ H1s,
                                                const int* __restrict__ row_ptr,
                                                const int* __restrict__ col,
                                                const float* __restrict__ dinv,
                                                const float* __restrict__ b1,
                                                const __half* __restrict__ W2T,
                                                __half* __restrict__ H2s) {
    __shared__ __align__(16) _Float16 rows[16][136];   // +8 pad: 16B-aligned, 2-way-max banks
    const int wave = threadIdx.x >> 6;
    const int lane = threadIdx.x & 63;
    const __half2* base = (const __half2*)H1s;   // row stride 64 half2
    const float2 bb = ((const float2*)b1)[lane];
    const int d00 = blockIdx.x * 16 + wave * 4;

    #pragma unroll
    for (int i = 0; i < 4; i++) {
        const int d = d00 + i;
        const int e0 = __builtin_amdgcn_readfirstlane(row_ptr[d]);
        const int e1 = __builtin_amdgcn_readfirstlane(row_ptr[d + 1]);
        const float dd = dinv[d];
        float ax = 0.f, ay = 0.f;
        int e = e0;
        for (; e + 7 < e1; e += 8) {
            int s0 = col[e],     s1 = col[e + 1], s2 = col[e + 2], s3 = col[e + 3];
            int s4 = col[e + 4], s5 = col[e + 5], s6 = col[e + 6], s7 = col[e + 7];
            float d0 = dinv[s0], d1 = dinv[s1], d2 = dinv[s2], d3 = dinv[s3];
            float d4 = dinv[s4], d5 = dinv[s5], d6 = dinv[s6], d7 = dinv[s7];
            float2 f0 = __half22float2(base[(long)s0 * 64 + lane]);
            float2 f1 = __half22float2(base[(long)s1 * 64 + lane]);
            float2 f2 = __half22float2(base[(long)s2 * 64 + lane]);
            float2 f3 = __half22float2(base[(long)s3 * 64 + lane]);
            float2 f4 = __half22float2(base[(long)s4 * 64 + lane]);
            float2 f5 = __half22float2(base[(long)s5 * 64 + lane]);
            float2 f6 = __half22float2(base[(long)s6 * 64 + lane]);
            float2 f7 = __half22float2(base[(long)s7 * 64 + lane]);
            ax += d0 * f0.x + d1 * f1.x + d2 * f2.x + d3 * f3.x
                + d4 * f4.x + d5 * f5.x + d6 * f6.x + d7 * f7.x;
            ay += d0 * f0.y + d1 * f1.y + d2 * f2.y + d3 * f3.y
                + d4 * f4.y + d5 * f5.y + d6 * f6.y + d7 * f7.y;
        }
        for (; e + 3 < e1; e += 4) {
            int s0 = col[e], s1 = col[e + 1], s2 = col[e + 2], s3 = col[e + 3];
            float d0 = dinv[s0], d1 = dinv[s1], d2 = dinv[s2], d3 = dinv[s3];
            float2 f0 = __half22float2(base[(long)s0 * 64 + lane]);
            float2 f1 = __half22float2(base[(long)s1 * 64 + lane]);
            float2 f2 = __half22float2(base[(long)s2 * 64 + lane]);
            float2 f3 = __half22float2(base[(long)s3 * 64 + lane]);
            ax += d0 * f0.x + d1 * f1.x + d2 * f2.x + d3 * f3.x;
            ay += d0 * f0.y + d1 * f1.y + d2 * f2.y + d3 * f3.y;
        }
        for (; e < e1; e++) {
            int s = col[e];
            float dv = dinv[s];
            float2 f = __half22float2(base[(long)s * 64 + lane]);
            ax += dv * f.x; ay += dv * f.y;
        }
        // self-loop (unscaled H1 row x dd)
        float2 fs = __half22float2(base[(long)d * 64 + lane]);
        ax += dd * fs.x; ay += dd * fs.y;
        // bias + relu, then pre-scale by dd so the layer-2 MFMA needs no post-scale
        float ox = fmaxf(dd * ax + bb.x, 0.f) * dd;
        float oy = fmaxf(dd * ay + bb.y, 0.f) * dd;
        *(__half2*)&rows[wave * 4 + i][lane * 2] =
            __halves2half2(__float2half_rn(ox), __float2half_rn(oy));
    }
    __syncthreads();

    if (wave < 3) {   // 3 n-tiles of 16 cols (48 padded, 40 real)
        const int m16 = lane & 15;
        const int kq  = lane >> 4;
        floatx4 acc = (floatx4)0.f;
        #pragma unroll
        for (int ks = 0; ks < 4; ks++) {
            half8 a = *(const half8*)&rows[m16][ks * 32 + kq * 8];
            half8 b = *(const half8*)&W2T[(wave * 16 + m16) * HIDDEN + ks * 32 + kq * 8];
            acc = __builtin_amdgcn_mfma_f32_16x16x32_f16(a, b, acc, 0, 0, 0);
        }
        const int c = wave * 16 + m16;
        if (c < NCLS) {
            const int gr0 = blockIdx.x * 16 + kq * 4;
            #pragma unroll
            for (int r = 0; r < 4; r++)
                H2s[(long)(gr0 + r) * NCLS + c] = __float2half_rn(acc[r]);
        }
    }
}

// ---------------- Aggregation 2 (+bias) -> fp32 out. 6 nodes x 10 half4-lanes per wave ----------------

__global__ __launch_bounds__(256) void k_agg2(const __half* __restrict__ H2s,
                                              const int* __restrict__ row_ptr,
                                              const int* __restrict__ col,
                                              const float* __restrict__ dinv,
                                              const float* __restrict__ b2,
                                              float* __restrict__ out) {
    const int wave = threadIdx.x >> 6;
    const int lane = threadIdx.x & 63;
    const int g = lane / 10;              // 0..5 active, lanes 60-63 idle
    const int f = lane - g * 10;          // 0..9 -> feats 4f..4f+3
    const int d = blockIdx.x * 24 + wave * 6 + g;
    const bool act = (g < 6) && (d < N_NODES);
    int e0 = 0, e1 = 0;
    if (act) { e0 = row_ptr[d]; e1 = row_ptr[d + 1]; }
    const half4f* base4 = (const half4f*)H2s;   // row stride 10 half4
    float s0 = 0.f, s1 = 0.f, s2 = 0.f, s3 = 0.f;
    int e = e0;
    while (__any(e < e1)) {
        #pragma unroll
        for (int u = 0; u < 8; u++) {     // 8 gathers in flight per group
            if (e + u < e1) {
                half4f v = base4[(long)col[e + u] * 10 + f];
                s0 += (float)v[0]; s1 += (float)v[1]; s2 += (float)v[2]; s3 += (float)v[3];
            }
        }
        e += 8;
    }
    if (act) {
        half4f v = base4[(long)d * 10 + f];   // self-loop (pre-scaled)
        s0 += (float)v[0]; s1 += (float)v[1]; s2 += (float)v[2]; s3 += (float)v[3];
        float dd = dinv[d];
        float4 bbv = ((const float4*)b2)[f];
        float4 o = make_float4(dd * s0 + bbv.x, dd * s1 + bbv.y, dd * s2 + bbv.z, dd * s3 + bbv.w);
        ((float4*)out)[(long)d * 10 + f] = o;
    }
}

// ---------------- launch ----------------

extern "C" void kernel_launch(void* const* d_in, const int* in_sizes, int n_in,
                              void* d_out, int out_size, void* d_ws, size_t ws_size,
                              hipStream_t stream) {
    const float* x  = (const float*)d_in[0];
    const int*   ei = (const int*)d_in[1];
    const float* W1 = (const float*)d_in[2];
    const float* b1 = (const float*)d_in[3];
    const float* W2 = (const float*)d_in[4];
    const float* b2 = (const float*)d_in[5];
    const int* srcE = ei;
    const int* dstE = ei + N_EDGES;

    int*   row_ptr = (int*)d_ws;                    // 100032 ints
    int*   bfill   = row_ptr + 100032;              // 256
    int*   col     = bfill + 256;                   // 1600000
    float* dinv    = (float*)(col + N_EDGES);       // 100032 floats
    __half* H1s    = (__half*)(dinv + 100032);      // 12.8M halfs (25.6 MB)
    __half* H2s    = H1s + (long)N_NODES * HIDDEN;  // 4M halfs (8 MB)
    __half* W1T    = H2s + (long)N_NODES * NCLS;    // 32768 halfs
    __half* W2T    = W1T + IN_DIM * HIDDEN;         // 6144 halfs
    unsigned long long* bpair = (unsigned long long*)(W2T + NCLS_PAD * HIDDEN);  // 2.1M (16.8 MB)

    k_prep   <<<130, 256, 0, stream>>>(W1, W1T, W2, W2T, bfill);
    k_binmm  <<<BIN_BLOCKS + GEMM1_BLOCKS, 256, 0, stream>>>(srcE, dstE, bfill, bpair, x, W1T, H1s);
    k_build  <<<N_BUCKETS, 256, 0, stream>>>(bfill, bpair, row_ptr, dinv, col);
    k_agg1g2 <<<N_NODES / 16, 256, 0, stream>>>(H1s, row_ptr, col, dinv, b1, W2T, H2s);
    k_agg2   <<<(N_NODES + 23) / 24, 256, 0, stream>>>(H2s, row_ptr, col, dinv, b2, (float*)d_out);
}

// Round 7
// 334.183 us; speedup vs baseline: 1.0414x; 1.0414x over previous
//
#include <hip/hip_runtime.h>
#include <hip/hip_bf16.h>
#include <hip/hip_fp16.h>

#define N_NODES 100000
#define N_EDGES 1600000
#define IN_DIM 256
#define HIDDEN 128
#define NCLS 40
#define NCLS_PAD 48      // padded to 3 MFMA n-tiles

#define N_BUCKETS 256
#define NPB 391          // nodes per bucket = ceil(100000/256)
#define BCAP 8192        // bucket capacity (mean 6256, +24 sigma)
#define EPT 16           // edges per thread in bin phase
#define BIN_WG 4096      // edges per workgroup (256*16)
#define BIN_BLOCKS 391   // ceil(N_EDGES / BIN_WG)
#define GEMM1_BLOCKS 782 // ceil(N_NODES / 128)

typedef __attribute__((ext_vector_type(8))) _Float16 half8;
typedef __attribute__((ext_vector_type(4))) _Float16 half4f;
typedef __attribute__((ext_vector_type(4))) float floatx4;

// ---------------- k_prep: W1T / W2T fp16 transposes + bfill zero ----------------

__global__ __launch_bounds__(256) void k_prep(const float* __restrict__ W1, __half* __restrict__ W1T,
                                              const float* __restrict__ W2, __half* __restrict__ W2T,
                                              int* __restrict__ bfill) {
    const int t = threadIdx.x;
    if (blockIdx.x < 128) {              // W1T: [n][k] fp16, 128 x 256
        int i = blockIdx.x * 256 + t;
        int k = i >> 7, n = i & 127;
        W1T[n * IN_DIM + k] = __float2half_rn(W1[i]);
    } else if (blockIdx.x == 128) {      // W2T: [n][k] fp16, 48 x 128, zero-pad n>=40
        for (int i = t; i < NCLS_PAD * HIDDEN; i += 256) {
            int n = i >> 7, k = i & 127;
            W2T[n * HIDDEN + k] = (n < NCLS) ? __float2half_rn(W2[k * NCLS + n]) : __float2half_rn(0.f);
        }
    } else {
        bfill[t] = 0;
    }
}

// ---------------- k_binmm: [0,391) LDS-staged edge binning  ∥  [391,1173) GEMM1 (unscaled) ----------------
// Bin phase: round-3 proven config (256 buckets, bid[], 128B/bucket scatter chunks).
// GEMM phase: B staged in LDS once per k-half (Bsm[128][136] = 34.8KB <= bin's 39.9KB
// union -> residency unchanged); A read DIRECTLY per-lane from X (32 rows/wave,
// 128B-contiguous per row, depth-1 register prefetch). K-loop has ZERO barriers
// (3 per block total vs 8): per step = prefetch-next-A -> cvt -> 8 ds_read_b128 +
// 16 MFMA. No loadB register prefetch (rounds 5/6: correlated with 1.9x bpair
// write amplification via L2 pressure).

__global__ __launch_bounds__(256) void k_binmm(const int* __restrict__ src, const int* __restrict__ dst,
                                               int* __restrict__ bfill,
                                               unsigned long long* __restrict__ bpair,
                                               const float* __restrict__ X,
                                               const __half* __restrict__ W1T,
                                               __half* __restrict__ H1s) {
    __shared__ __align__(16) char smraw[39936];   // union: bin(39936) / gemm1 Bsm(34816)
    const int t = threadIdx.x;

    if (blockIdx.x < BIN_BLOCKS) {
        // ---- bin phase ----
        int* hist   = (int*)smraw;                               // 256
        int* bstart = hist + 256;                                // 256
        int* gbase  = bstart + 256;                              // 256
        unsigned long long* stage = (unsigned long long*)(smraw + 3072);   // 4096 (32 KB)
        unsigned char* bid = (unsigned char*)(smraw + 3072 + 32768);       // 4096
        hist[t] = 0;
        __syncthreads();
        const long e0 = (long)blockIdx.x * BIN_WG;
        const int n_valid = (int)min((long)BIN_WG, (long)N_EDGES - e0);
        int msrc[EPT], mdst[EPT], moff[EPT];
        #pragma unroll
        for (int i = 0; i < EPT; i++) {
            long e = e0 + t + i * 256;
            if (e < N_EDGES) {
                msrc[i] = src[e];
                mdst[i] = dst[e];
                moff[i] = atomicAdd(&hist[mdst[i] / NPB], 1);
            } else {
                mdst[i] = -1;
            }
        }
        __syncthreads();
        if (t < 64) {   // wave 0: exclusive scan of hist[256]
            int carry = 0;
            #pragma unroll
            for (int c = 0; c < 4; c++) {
                int idx = c * 64 + t;
                int hv = hist[idx];
                int s = hv;
                #pragma unroll
                for (int d2 = 1; d2 < 64; d2 <<= 1) {
                    int u = __shfl_up(s, d2, 64);
                    if (t >= d2) s += u;
                }
                bstart[idx] = carry + (s - hv);
                carry += __shfl(s, 63, 64);
            }
        }
        __syncthreads();
        int h = hist[t];
        gbase[t] = (h > 0) ? atomicAdd(&bfill[t], h) : 0;
        #pragma unroll
        for (int i = 0; i < EPT; i++) {
            if (mdst[i] >= 0) {
                int b = mdst[i] / NPB;
                int pos = bstart[b] + moff[i];
                stage[pos] = ((unsigned long long)(unsigned)mdst[i] << 32) | (unsigned)msrc[i];
                bid[pos] = (unsigned char)b;
            }
        }
        __syncthreads();
        for (int i = t; i < n_valid; i += 256) {
            int b = bid[i];
            int dest = gbase[b] + (i - bstart[b]);
            bpair[(long)b * BCAP + dest] = stage[i];
        }
        return;
    }

    // ---- gemm1 phase (128x128 tile, MFMA f16, barrier-free k-loop) ----
    _Float16 (*Bsm)[136] = (_Float16(*)[136])smraw;   // 128 x 136 fp16 (+8 pad: +4 banks/row)
    const int wave = t >> 6;
    const int lane = t & 63;
    const int m16  = lane & 15;
    const int kq   = lane >> 4;
    const int row0 = (blockIdx.x - BIN_BLOCKS) * 128;
    const int arow0 = row0 + wave * 32 + m16;
    const int arow1 = arow0 + 16;
    const bool va0 = arow0 < N_NODES;
    const bool va1 = arow1 < N_NODES;
    const float* pX0 = X + (long)arow0 * IN_DIM + kq * 8;
    const float* pX1 = X + (long)arow1 * IN_DIM + kq * 8;
    const float4 z4 = make_float4(0.f, 0.f, 0.f, 0.f);

    floatx4 acc[2][8];
    #pragma unroll
    for (int mt = 0; mt < 2; mt++)
        #pragma unroll
        for (int i = 0; i < 8; i++) acc[mt][i] = (floatx4)0.f;

    float4 curA[2][2], nxtA[2][2];
    auto loadA2 = [&](float4 (*A)[2], int kbase) {
        if (va0) { A[0][0] = *(const float4*)(pX0 + kbase); A[0][1] = *(const float4*)(pX0 + kbase + 4); }
        else     { A[0][0] = z4; A[0][1] = z4; }
        if (va1) { A[1][0] = *(const float4*)(pX1 + kbase); A[1][1] = *(const float4*)(pX1 + kbase + 4); }
        else     { A[1][0] = z4; A[1][1] = z4; }
    };

    loadA2(curA, 0);     // issue first A load before B staging (HBM latency head start)

    #pragma unroll
    for (int h = 0; h < 2; h++) {        // two k-halves of 128
        // stage B half h: W1T[n][h*128 .. +128) -> Bsm[n][0..128)
        #pragma unroll
        for (int i = 0; i < 8; i++) {
            int c = t + i * 256;         // 2048 half8-chunks
            int n = c >> 4, k8 = c & 15;
            *(half8*)&Bsm[n][k8 * 8] = *(const half8*)&W1T[n * IN_DIM + h * 128 + k8 * 8];
        }
        __syncthreads();
        #pragma unroll
        for (int s = 0; s < 4; s++) {    // 4 k-steps of 32 per half
            if (!(h == 1 && s == 3)) {   // depth-1 A prefetch (crosses the half barrier)
                int kn = (s < 3) ? (h * 128 + (s + 1) * 32) : 128;
                loadA2(nxtA, kn);
            }
            half8 a0, a1;
            a0[0] = (_Float16)curA[0][0].x; a0[1] = (_Float16)curA[0][0].y;
            a0[2] = (_Float16)curA[0][0].z; a0[3] = (_Float16)curA[0][0].w;
            a0[4] = (_Float16)curA[0][1].x; a0[5] = (_Float16)curA[0][1].y;
            a0[6] = (_Float16)curA[0][1].z; a0[7] = (_Float16)curA[0][1].w;
            a1[0] = (_Float16)curA[1][0].x; a1[1] = (_Float16)curA[1][0].y;
            a1[2] = (_Float16)curA[1][0].z; a1[3] = (_Float16)curA[1][0].w;
            a1[4] = (_Float16)curA[1][1].x; a1[5] = (_Float16)curA[1][1].y;
            a1[6] = (_Float16)curA[1][1].z; a1[7] = (_Float16)curA[1][1].w;
            const _Float16* bbase = &Bsm[m16][s * 32 + kq * 8];
            #pragma unroll
            for (int nt = 0; nt < 8; nt++) {
                half8 b = *(const half8*)(bbase + nt * 16 * 136);
                acc[0][nt] = __builtin_amdgcn_mfma_f32_16x16x32_f16(a0, b, acc[0][nt], 0, 0, 0);
                acc[1][nt] = __builtin_amdgcn_mfma_f32_16x16x32_f16(a1, b, acc[1][nt], 0, 0, 0);
            }
            #pragma unroll
            for (int p = 0; p < 2; p++) { curA[p][0] = nxtA[p][0]; curA[p][1] = nxtA[p][1]; }
        }
        if (h == 0) __syncthreads();     // all waves done reading Bsm before restage
    }

    #pragma unroll
    for (int mt = 0; mt < 2; mt++) {
        const int gr0 = row0 + wave * 32 + mt * 16 + kq * 4;
        #pragma unroll
        for (int nt = 0; nt < 8; nt++) {
            int c = nt * 16 + m16;
            #pragma unroll
            for (int r = 0; r < 4; r++) {
                if (gr0 + r < N_NODES)
                    H1s[(long)(gr0 + r) * HIDDEN + c] = __float2half_rn(acc[mt][nt][r]);
            }
        }
    }
}

// ---------------- k_build: histogram -> prefix -> row_ptr/dinv -> scatter ----------------
// (no H1 scaling: dinv[src] folds into k_agg1g2 via SCALAR loads)

__global__ __launch_bounds__(256) void k_build(const int* __restrict__ bfill,
                                               const unsigned long long* __restrict__ bpair,
                                               int* __restrict__ row_ptr, float* __restrict__ dinv,
                                               int* __restrict__ col) {
    __shared__ int h[NPB];
    __shared__ int pfx[NPB];
    __shared__ int sred[4];
    const int b  = blockIdx.x;
    const int nb = b * NPB;
    const int nn = min(NPB, N_NODES - nb);
    const int t  = threadIdx.x;
    int v = (t < b) ? bfill[t] : 0;
    #pragma unroll
    for (int dl = 32; dl > 0; dl >>= 1) v += __shfl_down(v, dl, 64);
    if ((t & 63) == 0) sred[t >> 6] = v;
    for (int i = t; i < NPB; i += 256) h[i] = 0;
    __syncthreads();
    const int base_b = sred[0] + sred[1] + sred[2] + sred[3];
    const int n = bfill[b];
    for (int i = t; i < n; i += 256) {
        int dd = (int)(bpair[(long)b * BCAP + i] >> 32);
        atomicAdd(&h[dd - nb], 1);
    }
    __syncthreads();
    if (t < 64) {   // wave 0: exclusive scan of degrees
        int carry = 0;
        #pragma unroll
        for (int c = 0; c < (NPB + 63) / 64; c++) {
            int idx = c * 64 + t;
            int hv = (idx < nn) ? h[idx] : 0;
            int s = hv;
            #pragma unroll
            for (int d2 = 1; d2 < 64; d2 <<= 1) {
                int u = __shfl_up(s, d2, 64);
                if (t >= d2) s += u;
            }
            if (idx < nn) {
                int ex = base_b + carry + (s - hv);
                pfx[idx] = ex;
                row_ptr[nb + idx] = ex;
                dinv[nb + idx] = rsqrtf((float)(hv + 1));   // +1 self-loop
            }
            carry += __shfl(s, 63, 64);
        }
    }
    __syncthreads();
    for (int i = t; i < nn; i += 256) h[i] = 0;   // reuse as fill counters
    __syncthreads();
    for (int i = t; i < n; i += 256) {
        unsigned long long p = bpair[(long)b * BCAP + i];
        int dd = (int)(p >> 32);
        int ss = (int)(p & 0xFFFFFFFFu);
        int pos = pfx[dd - nb] + atomicAdd(&h[dd - nb], 1);
        col[pos] = ss;
    }
    if (b == 0 && t == 0) row_ptr[N_NODES] = N_EDGES;
}

// ---------------- k_agg1g2: Agg1 (+bias+ReLU, pre-scale) + MFMA GEMM2 -> H2s fp16 ----------------
// Block = 16 nodes, each wave serially aggregates 4 nodes with a full-row gather per
// edge (64 lanes x half2 = 256B). e0/e1 forced to SGPR via readfirstlane so col[e..]
// are SGPR scalar loads; therefore dinv[col[e]] are ALSO uniform-address scalar loads
// (SMEM pipe, overlapped with the VMEM gathers) and the sym-norm scale folds into the
// accumulate as fmac-with-SGPR — no separate H1-scale pass anywhere. 8 gathers in flight.

__global__ __launch_bounds__(256) void k_agg1g2(const __half* __restrict__ H1s,
                                                const int* __restrict__ row_ptr,
                                                const int* __restrict__ col,
                                                const float* __restrict__ dinv,
                                                const float* __restrict__ b1,
                                                const __half* __restrict__ W2T,
                                                __half* __restrict__ H2s) {
    __shared__ __align__(16) _Float16 rows[16][136];   // +8 pad: 16B-aligned, 2-way-max banks
    const int wave = threadIdx.x >> 6;
    const int lane = threadIdx.x & 63;
    const __half2* base = (const __half2*)H1s;   // row stride 64 half2
    const float2 bb = ((const float2*)b1)[lane];
    const int d00 = blockIdx.x * 16 + wave * 4;

    #pragma unroll
    for (int i = 0; i < 4; i++) {
        const int d = d00 + i;
        const int e0 = __builtin_amdgcn_readfirstlane(row_ptr[d]);
        const int e1 = __builtin_amdgcn_readfirstlane(row_ptr[d + 1]);
        const float dd = dinv[d];
        float ax = 0.f, ay = 0.f;
        int e = e0;
        for (; e + 7 < e1; e += 8) {
            int s0 = col[e],     s1 = col[e + 1], s2 = col[e + 2], s3 = col[e + 3];
            int s4 = col[e + 4], s5 = col[e + 5], s6 = col[e + 6], s7 = col[e + 7];
            float d0 = dinv[s0], d1 = dinv[s1], d2 = dinv[s2], d3 = dinv[s3];
            float d4 = dinv[s4], d5 = dinv[s5], d6 = dinv[s6], d7 = dinv[s7];
            float2 f0 = __half22float2(base[(long)s0 * 64 + lane]);
            float2 f1 = __half22float2(base[(long)s1 * 64 + lane]);
            float2 f2 = __half22float2(base[(long)s2 * 64 + lane]);
            float2 f3 = __half22float2(base[(long)s3 * 64 + lane]);
            float2 f4 = __half22float2(base[(long)s4 * 64 + lane]);
            float2 f5 = __half22float2(base[(long)s5 * 64 + lane]);
            float2 f6 = __half22float2(base[(long)s6 * 64 + lane]);
            float2 f7 = __half22float2(base[(long)s7 * 64 + lane]);
            ax += d0 * f0.x + d1 * f1.x + d2 * f2.x + d3 * f3.x
                + d4 * f4.x + d5 * f5.x + d6 * f6.x + d7 * f7.x;
            ay += d0 * f0.y + d1 * f1.y + d2 * f2.y + d3 * f3.y
                + d4 * f4.y + d5 * f5.y + d6 * f6.y + d7 * f7.y;
        }
        for (; e + 3 < e1; e += 4) {
            int s0 = col[e], s1 = col[e + 1], s2 = col[e + 2], s3 = col[e + 3];
            float d0 = dinv[s0], d1 = dinv[s1], d2 = dinv[s2], d3 = dinv[s3];
            float2 f0 = __half22float2(base[(long)s0 * 64 + lane]);
            float2 f1 = __half22float2(base[(long)s1 * 64 + lane]);
            float2 f2 = __half22float2(base[(long)s2 * 64 + lane]);
            float2 f3 = __half22float2(base[(long)s3 * 64 + lane]);
            ax += d0 * f0.x + d1 * f1.x + d2 * f2.x + d3 * f3.x;
            ay += d0 * f0.y + d1 * f1.y + d2 * f2.y + d3 * f3.y;
        }
        for (; e < e1; e++) {
            int s = col[e];
            float dv = dinv[s];
            float2 f = __half22float2(base[(long)s * 64 + lane]);
            ax += dv * f.x; ay += dv * f.y;
        }
        // self-loop (unscaled H1 row x dd)
        float2 fs = __half22float2(base[(long)d * 64 + lane]);
        ax += dd * fs.x; ay += dd * fs.y;
        // bias + relu, then pre-scale by dd so the layer-2 MFMA needs no post-scale
        float ox = fmaxf(dd * ax + bb.x, 0.f) * dd;
        float oy = fmaxf(dd * ay + bb.y, 0.f) * dd;
        *(__half2*)&rows[wave * 4 + i][lane * 2] =
            __halves2half2(__float2half_rn(ox), __float2half_rn(oy));
    }
    __syncthreads();

    if (wave < 3) {   // 3 n-tiles of 16 cols (48 padded, 40 real)
        const int m16 = lane & 15;
        const int kq  = lane >> 4;
        floatx4 acc = (floatx4)0.f;
        #pragma unroll
        for (int ks = 0; ks < 4; ks++) {
            half8 a = *(const half8*)&rows[m16][ks * 32 + kq * 8];
            half8 b = *(const half8*)&W2T[(wave * 16 + m16) * HIDDEN + ks * 32 + kq * 8];
            acc = __builtin_amdgcn_mfma_f32_16x16x32_f16(a, b, acc, 0, 0, 0);
        }
        const int c = wave * 16 + m16;
        if (c < NCLS) {
            const int gr0 = blockIdx.x * 16 + kq * 4;
            #pragma unroll
            for (int r = 0; r < 4; r++)
                H2s[(long)(gr0 + r) * NCLS + c] = __float2half_rn(acc[r]);
        }
    }
}

// ---------------- Aggregation 2 (+bias) -> fp32 out. 6 nodes x 10 half4-lanes per wave ----------------

__global__ __launch_bounds__(256) void k_agg2(const __half* __restrict__ H2s,
                                              const int* __restrict__ row_ptr,
                                              const int* __restrict__ col,
                                              const float* __restrict__ dinv,
                                              const float* __restrict__ b2,
                                              float* __restrict__ out) {
    const int wave = threadIdx.x >> 6;
    const int lane = threadIdx.x & 63;
    const int g = lane / 10;              // 0..5 active, lanes 60-63 idle
    const int f = lane - g * 10;          // 0..9 -> feats 4f..4f+3
    const int d = blockIdx.x * 24 + wave * 6 + g;
    const bool act = (g < 6) && (d < N_NODES);
    int e0 = 0, e1 = 0;
    if (act) { e0 = row_ptr[d]; e1 = row_ptr[d + 1]; }
    const half4f* base4 = (const half4f*)H2s;   // row stride 10 half4
    float s0 = 0.f, s1 = 0.f, s2 = 0.f, s3 = 0.f;
    int e = e0;
    while (__any(e < e1)) {
        #pragma unroll
        for (int u = 0; u < 8; u++) {     // 8 gathers in flight per group
            if (e + u < e1) {
                half4f v = base4[(long)col[e + u] * 10 + f];
                s0 += (float)v[0]; s1 += (float)v[1]; s2 += (float)v[2]; s3 += (float)v[3];
            }
        }
        e += 8;
    }
    if (act) {
        half4f v = base4[(long)d * 10 + f];   // self-loop (pre-scaled)
        s0 += (float)v[0]; s1 += (float)v[1]; s2 += (float)v[2]; s3 += (float)v[3];
        float dd = dinv[d];
        float4 bbv = ((const float4*)b2)[f];
        float4 o = make_float4(dd * s0 + bbv.x, dd * s1 + bbv.y, dd * s2 + bbv.z, dd * s3 + bbv.w);
        ((float4*)out)[(long)d * 10 + f] = o;
    }
}

// ---------------- launch ----------------

extern "C" void kernel_launch(void* const* d_in, const int* in_sizes, int n_in,
                              void* d_out, int out_size, void* d_ws, size_t ws_size,
                              hipStream_t stream) {
    const float* x  = (const float*)d_in[0];
    const int*   ei = (const int*)d_in[1];
    const float* W1 = (const float*)d_in[2];
    const float* b1 = (const float*)d_in[3];
    const float* W2 = (const float*)d_in[4];
    const float* b2 = (const float*)d_in[5];
    const int* srcE = ei;
    const int* dstE = ei + N_EDGES;

    int*   row_ptr = (int*)d_ws;                    // 100032 ints
    int*   bfill   = row_ptr + 100032;              // 256
    int*   col     = bfill + 256;                   // 1600000
    float* dinv    = (float*)(col + N_EDGES);       // 100032 floats
    __half* H1s    = (__half*)(dinv + 100032);      // 12.8M halfs (25.6 MB)
    __half* H2s    = H1s + (long)N_NODES * HIDDEN;  // 4M halfs (8 MB)
    __half* W1T    = H2s + (long)N_NODES * NCLS;    // 32768 halfs
    __half* W2T    = W1T + IN_DIM * HIDDEN;         // 6144 halfs
    unsigned long long* bpair = (unsigned long long*)(W2T + NCLS_PAD * HIDDEN);  // 2.1M (16.8 MB)

    k_prep   <<<130, 256, 0, stream>>>(W1, W1T, W2, W2T, bfill);
    k_binmm  <<<BIN_BLOCKS + GEMM1_BLOCKS, 256, 0, stream>>>(srcE, dstE, bfill, bpair, x, W1T, H1s);
    k_build  <<<N_BUCKETS, 256, 0, stream>>>(bfill, bpair, row_ptr, dinv, col);
    k_agg1g2 <<<N_NODES / 16, 256, 0, stream>>>(H1s, row_ptr, col, dinv, b1, W2T, H2s);
    k_agg2   <<<(N_NODES + 23) / 24, 256, 0, stream>>>(H2s, row_ptr, col, dinv, b2, (float*)d_out);
}

// Round 8
// 328.954 us; speedup vs baseline: 1.0579x; 1.0159x over previous
//
#include <hip/hip_runtime.h>
#include <hip/hip_bf16.h>
#include <hip/hip_fp16.h>

#define N_NODES 100000
#define N_EDGES 1600000
#define IN_DIM 256
#define HIDDEN 128
#define NCLS 40
#define NCLS_PAD 48      // padded to 3 MFMA n-tiles

#define N_BUCKETS 256
#define NPB 391          // nodes per bucket = ceil(100000/256)
#define BCAP 8192        // bucket capacity (mean 6256, +24 sigma)
#define EPT 16           // edges per thread in bin phase
#define BIN_WG 4096      // edges per workgroup (256*16)
#define BIN_BLOCKS 391   // ceil(N_EDGES / BIN_WG)
#define GEMM1_BLOCKS 782 // ceil(N_NODES / 128)

typedef __attribute__((ext_vector_type(8))) _Float16 half8;
typedef __attribute__((ext_vector_type(4))) _Float16 half4f;
typedef __attribute__((ext_vector_type(4))) float floatx4;

// ---------------- k_prep: W1T / W2T fp16 transposes + bfill zero ----------------

__global__ __launch_bounds__(256) void k_prep(const float* __restrict__ W1, __half* __restrict__ W1T,
                                              const float* __restrict__ W2, __half* __restrict__ W2T,
                                              int* __restrict__ bfill) {
    const int t = threadIdx.x;
    if (blockIdx.x < 128) {              // W1T: [n][k] fp16, 128 x 256
        int i = blockIdx.x * 256 + t;
        int k = i >> 7, n = i & 127;
        W1T[n * IN_DIM + k] = __float2half_rn(W1[i]);
    } else if (blockIdx.x == 128) {      // W2T: [n][k] fp16, 48 x 128, zero-pad n>=40
        for (int i = t; i < NCLS_PAD * HIDDEN; i += 256) {
            int n = i >> 7, k = i & 127;
            W2T[n * HIDDEN + k] = (n < NCLS) ? __float2half_rn(W2[k * NCLS + n]) : __float2half_rn(0.f);
        }
    } else {
        bfill[t] = 0;
    }
}

// ---------------- k_binmm: [0,391) LDS-staged edge binning  ∥  [391,1173) GEMM1 (unscaled) ----------------
// Bin phase: round-3 proven config (256 buckets, bid[], 128B/bucket scatter chunks).
// GEMM phase: B staged in LDS once per k-half (Bsm[128][136] = 34.8KB); A read
// DIRECTLY per-lane from X with DEPTH-2 register prefetch (3 rotating buffers, all
// indices compile-time after full unroll) — ~8KB/wave in flight, exposed HBM stall
// per k-step cut from ~650 to ~400 cy. K-loop has no per-step barriers. No B register
// prefetch (rounds 5/6: correlated with 1.9x bpair write amplification).

__global__ __launch_bounds__(256) void k_binmm(const int* __restrict__ src, const int* __restrict__ dst,
                                               int* __restrict__ bfill,
                                               unsigned long long* __restrict__ bpair,
                                               const float* __restrict__ X,
                                               const __half* __restrict__ W1T,
                                               __half* __restrict__ H1s) {
    __shared__ __align__(16) char smraw[39936];   // union: bin(39936) / gemm1 Bsm(34816)
    const int t = threadIdx.x;

    if (blockIdx.x < BIN_BLOCKS) {
        // ---- bin phase ----
        int* hist   = (int*)smraw;                               // 256
        int* bstart = hist + 256;                                // 256
        int* gbase  = bstart + 256;                              // 256
        unsigned long long* stage = (unsigned long long*)(smraw + 3072);   // 4096 (32 KB)
        unsigned char* bid = (unsigned char*)(smraw + 3072 + 32768);       // 4096
        hist[t] = 0;
        __syncthreads();
        const long e0 = (long)blockIdx.x * BIN_WG;
        const int n_valid = (int)min((long)BIN_WG, (long)N_EDGES - e0);
        int msrc[EPT], mdst[EPT], moff[EPT];
        #pragma unroll
        for (int i = 0; i < EPT; i++) {
            long e = e0 + t + i * 256;
            if (e < N_EDGES) {
                msrc[i] = src[e];
                mdst[i] = dst[e];
                moff[i] = atomicAdd(&hist[mdst[i] / NPB], 1);
            } else {
                mdst[i] = -1;
            }
        }
        __syncthreads();
        if (t < 64) {   // wave 0: exclusive scan of hist[256]
            int carry = 0;
            #pragma unroll
            for (int c = 0; c < 4; c++) {
                int idx = c * 64 + t;
                int hv = hist[idx];
                int s = hv;
                #pragma unroll
                for (int d2 = 1; d2 < 64; d2 <<= 1) {
                    int u = __shfl_up(s, d2, 64);
                    if (t >= d2) s += u;
                }
                bstart[idx] = carry + (s - hv);
                carry += __shfl(s, 63, 64);
            }
        }
        __syncthreads();
        int h = hist[t];
        gbase[t] = (h > 0) ? atomicAdd(&bfill[t], h) : 0;
        #pragma unroll
        for (int i = 0; i < EPT; i++) {
            if (mdst[i] >= 0) {
                int b = mdst[i] / NPB;
                int pos = bstart[b] + moff[i];
                stage[pos] = ((unsigned long long)(unsigned)mdst[i] << 32) | (unsigned)msrc[i];
                bid[pos] = (unsigned char)b;
            }
        }
        __syncthreads();
        for (int i = t; i < n_valid; i += 256) {
            int b = bid[i];
            int dest = gbase[b] + (i - bstart[b]);
            bpair[(long)b * BCAP + dest] = stage[i];
        }
        return;
    }

    // ---- gemm1 phase (128x128 tile, MFMA f16, depth-2 A prefetch) ----
    _Float16 (*Bsm)[136] = (_Float16(*)[136])smraw;   // 128 x 136 fp16 (+8 pad: +4 banks/row)
    const int wave = t >> 6;
    const int lane = t & 63;
    const int m16  = lane & 15;
    const int kq   = lane >> 4;
    const int row0 = (blockIdx.x - BIN_BLOCKS) * 128;
    const int arow0 = row0 + wave * 32 + m16;
    const int arow1 = arow0 + 16;
    const bool va0 = arow0 < N_NODES;
    const bool va1 = arow1 < N_NODES;
    const float* pX0 = X + (long)arow0 * IN_DIM + kq * 8;
    const float* pX1 = X + (long)arow1 * IN_DIM + kq * 8;
    const float4 z4 = make_float4(0.f, 0.f, 0.f, 0.f);

    floatx4 acc[2][8];
    #pragma unroll
    for (int mt = 0; mt < 2; mt++)
        #pragma unroll
        for (int i = 0; i < 8; i++) acc[mt][i] = (floatx4)0.f;

    float4 A[3][2][2];   // 3 rotating depth-2 prefetch buffers (48 VGPR)
    auto loadA3 = [&](int buf, int kbase) {
        if (va0) { A[buf][0][0] = *(const float4*)(pX0 + kbase); A[buf][0][1] = *(const float4*)(pX0 + kbase + 4); }
        else     { A[buf][0][0] = z4; A[buf][0][1] = z4; }
        if (va1) { A[buf][1][0] = *(const float4*)(pX1 + kbase); A[buf][1][1] = *(const float4*)(pX1 + kbase + 4); }
        else     { A[buf][1][0] = z4; A[buf][1][1] = z4; }
    };

    loadA3(0, 0);        // prologue: steps 0 and 1 in flight before B staging
    loadA3(1, 32);

    #pragma unroll
    for (int h = 0; h < 2; h++) {        // two k-halves of 128
        // stage B half h: W1T[n][h*128 .. +128) -> Bsm[n][0..128)
        #pragma unroll
        for (int i = 0; i < 8; i++) {
            int c = t + i * 256;         // 2048 half8-chunks
            int n = c >> 4, k8 = c & 15;
            *(half8*)&Bsm[n][k8 * 8] = *(const half8*)&W1T[n * IN_DIM + h * 128 + k8 * 8];
        }
        __syncthreads();
        #pragma unroll
        for (int s4 = 0; s4 < 4; s4++) { // 4 k-steps of 32 per half
            const int s = h * 4 + s4;    // global step 0..7 (compile-time)
            if (s + 2 < 8) loadA3((s + 2) % 3, (s + 2) * 32);   // depth-2 prefetch
            const float4 (*cA)[2] = A[s % 3];
            half8 a0, a1;
            a0[0] = (_Float16)cA[0][0].x; a0[1] = (_Float16)cA[0][0].y;
            a0[2] = (_Float16)cA[0][0].z; a0[3] = (_Float16)cA[0][0].w;
            a0[4] = (_Float16)cA[0][1].x; a0[5] = (_Float16)cA[0][1].y;
            a0[6] = (_Float16)cA[0][1].z; a0[7] = (_Float16)cA[0][1].w;
            a1[0] = (_Float16)cA[1][0].x; a1[1] = (_Float16)cA[1][0].y;
            a1[2] = (_Float16)cA[1][0].z; a1[3] = (_Float16)cA[1][0].w;
            a1[4] = (_Float16)cA[1][1].x; a1[5] = (_Float16)cA[1][1].y;
            a1[6] = (_Float16)cA[1][1].z; a1[7] = (_Float16)cA[1][1].w;
            const _Float16* bbase = &Bsm[m16][s4 * 32 + kq * 8];
            #pragma unroll
            for (int nt = 0; nt < 8; nt++) {
                half8 b = *(const half8*)(bbase + nt * 16 * 136);
                acc[0][nt] = __builtin_amdgcn_mfma_f32_16x16x32_f16(a0, b, acc[0][nt], 0, 0, 0);
                acc[1][nt] = __builtin_amdgcn_mfma_f32_16x16x32_f16(a1, b, acc[1][nt], 0, 0, 0);
            }
        }
        if (h == 0) __syncthreads();     // all waves done reading Bsm before restage
    }

    #pragma unroll
    for (int mt = 0; mt < 2; mt++) {
        const int gr0 = row0 + wave * 32 + mt * 16 + kq * 4;
        #pragma unroll
        for (int nt = 0; nt < 8; nt++) {
            int c = nt * 16 + m16;
            #pragma unroll
            for (int r = 0; r < 4; r++) {
                if (gr0 + r < N_NODES)
                    H1s[(long)(gr0 + r) * HIDDEN + c] = __float2half_rn(acc[mt][nt][r]);
            }
        }
    }
}

// ---------------- k_build: histogram -> prefix -> row_ptr/dinv -> scatter ----------------
// 512 threads/block (8 waves/CU vs 4): TLP for the atomic/gather loops.

__global__ __launch_bounds__(512) void k_build(const int* __restrict__ bfill,
                                               const unsigned long long* __restrict__ bpair,
                                               int* __restrict__ row_ptr, float* __restrict__ dinv,
                                               int* __restrict__ col) {
    __shared__ int h[NPB];
    __shared__ int pfx[NPB];
    __shared__ int sred[8];
    const int b  = blockIdx.x;
    const int nb = b * NPB;
    const int nn = min(NPB, N_NODES - nb);
    const int t  = threadIdx.x;
    int v = (t < b) ? bfill[t] : 0;      // t in [0,512); bfill has 256 entries, b<=255 guards
    #pragma unroll
    for (int dl = 32; dl > 0; dl >>= 1) v += __shfl_down(v, dl, 64);
    if ((t & 63) == 0) sred[t >> 6] = v;
    for (int i = t; i < NPB; i += 512) h[i] = 0;
    __syncthreads();
    int base_b = 0;
    #pragma unroll
    for (int i = 0; i < 8; i++) base_b += sred[i];
    const int n = bfill[b];
    for (int i = t; i < n; i += 512) {
        int dd = (int)(bpair[(long)b * BCAP + i] >> 32);
        atomicAdd(&h[dd - nb], 1);
    }
    __syncthreads();
    if (t < 64) {   // wave 0: exclusive scan of degrees
        int carry = 0;
        #pragma unroll
        for (int c = 0; c < (NPB + 63) / 64; c++) {
            int idx = c * 64 + t;
            int hv = (idx < nn) ? h[idx] : 0;
            int s = hv;
            #pragma unroll
            for (int d2 = 1; d2 < 64; d2 <<= 1) {
                int u = __shfl_up(s, d2, 64);
                if (t >= d2) s += u;
            }
            if (idx < nn) {
                int ex = base_b + carry + (s - hv);
                pfx[idx] = ex;
                row_ptr[nb + idx] = ex;
                dinv[nb + idx] = rsqrtf((float)(hv + 1));   // +1 self-loop
            }
            carry += __shfl(s, 63, 64);
        }
    }
    __syncthreads();
    for (int i = t; i < nn; i += 512) h[i] = 0;   // reuse as fill counters
    __syncthreads();
    for (int i = t; i < n; i += 512) {
        unsigned long long p = bpair[(long)b * BCAP + i];
        int dd = (int)(p >> 32);
        int ss = (int)(p & 0xFFFFFFFFu);
        int pos = pfx[dd - nb] + atomicAdd(&h[dd - nb], 1);
        col[pos] = ss;
    }
    if (b == 0 && t == 0) row_ptr[N_NODES] = N_EDGES;
}

// ---------------- k_agg1g2: Agg1 (+bias+ReLU, pre-scale) + MFMA GEMM2 -> H2s fp16 ----------------
// Block = 16 nodes, each wave serially aggregates 4 nodes with a full-row gather per
// edge (64 lanes x half2 = 256B). e0/e1 forced to SGPR via readfirstlane so col[e..]
// are SGPR scalar loads; therefore dinv[col[e]] are ALSO uniform-address scalar loads
// (SMEM pipe, overlapped with the VMEM gathers) and the sym-norm scale folds into the
// accumulate as fmac-with-SGPR — no separate H1-scale pass anywhere. 8 gathers in flight.

__global__ __launch_bounds__(256) void k_agg1g2(const __half* __restrict__ H1s,
                                                const int* __restrict__ row_ptr,
                                                const int* __restrict__ col,
                                                const float* __restrict__ dinv,
                                                const float* __restrict__ b1,
                                                const __half* __restrict__ W2T,
                                                __half* __restrict__ H2s) {
    __shared__ __align__(16) _Float16 rows[16][136];   // +8 pad: 16B-aligned, 2-way-max banks
    const int wave = threadIdx.x >> 6;
    const int lane = threadIdx.x & 63;
    const __half2* base = (const __half2*)H1s;   // row stride 64 half2
    const float2 bb = ((const float2*)b1)[lane];
    const int d00 = blockIdx.x * 16 + wave * 4;

    #pragma unroll
    for (int i = 0; i < 4; i++) {
        const int d = d00 + i;
        const int e0 = __builtin_amdgcn_readfirstlane(row_ptr[d]);
        const int e1 = __builtin_amdgcn_readfirstlane(row_ptr[d + 1]);
        const float dd = dinv[d];
        float ax = 0.f, ay = 0.f;
        int e = e0;
        for (; e + 7 < e1; e += 8) {
            int s0 = col[e],     s1 = col[e + 1], s2 = col[e + 2], s3 = col[e + 3];
            int s4 = col[e + 4], s5 = col[e + 5], s6 = col[e + 6], s7 = col[e + 7];
            float d0 = dinv[s0], d1 = dinv[s1], d2 = dinv[s2], d3 = dinv[s3];
            float d4 = dinv[s4], d5 = dinv[s5], d6 = dinv[s6], d7 = dinv[s7];
            float2 f0 = __half22float2(base[(long)s0 * 64 + lane]);
            float2 f1 = __half22float2(base[(long)s1 * 64 + lane]);
            float2 f2 = __half22float2(base[(long)s2 * 64 + lane]);
            float2 f3 = __half22float2(base[(long)s3 * 64 + lane]);
            float2 f4 = __half22float2(base[(long)s4 * 64 + lane]);
            float2 f5 = __half22float2(base[(long)s5 * 64 + lane]);
            float2 f6 = __half22float2(base[(long)s6 * 64 + lane]);
            float2 f7 = __half22float2(base[(long)s7 * 64 + lane]);
            ax += d0 * f0.x + d1 * f1.x + d2 * f2.x + d3 * f3.x
                + d4 * f4.x + d5 * f5.x + d6 * f6.x + d7 * f7.x;
            ay += d0 * f0.y + d1 * f1.y + d2 * f2.y + d3 * f3.y
                + d4 * f4.y + d5 * f5.y + d6 * f6.y + d7 * f7.y;
        }
        for (; e + 3 < e1; e += 4) {
            int s0 = col[e], s1 = col[e + 1], s2 = col[e + 2], s3 = col[e + 3];
            float d0 = dinv[s0], d1 = dinv[s1], d2 = dinv[s2], d3 = dinv[s3];
            float2 f0 = __half22float2(base[(long)s0 * 64 + lane]);
            float2 f1 = __half22float2(base[(long)s1 * 64 + lane]);
            float2 f2 = __half22float2(base[(long)s2 * 64 + lane]);
            float2 f3 = __half22float2(base[(long)s3 * 64 + lane]);
            ax += d0 * f0.x + d1 * f1.x + d2 * f2.x + d3 * f3.x;
            ay += d0 * f0.y + d1 * f1.y + d2 * f2.y + d3 * f3.y;
        }
        for (; e < e1; e++) {
            int s = col[e];
            float dv = dinv[s];
            float2 f = __half22float2(base[(long)s * 64 + lane]);
            ax += dv * f.x; ay += dv * f.y;
        }
        // self-loop (unscaled H1 row x dd)
        float2 fs = __half22float2(base[(long)d * 64 + lane]);
        ax += dd * fs.x; ay += dd * fs.y;
        // bias + relu, then pre-scale by dd so the layer-2 MFMA needs no post-scale
        float ox = fmaxf(dd * ax + bb.x, 0.f) * dd;
        float oy = fmaxf(dd * ay + bb.y, 0.f) * dd;
        *(__half2*)&rows[wave * 4 + i][lane * 2] =
            __halves2half2(__float2half_rn(ox), __float2half_rn(oy));
    }
    __syncthreads();

    if (wave < 3) {   // 3 n-tiles of 16 cols (48 padded, 40 real)
        const int m16 = lane & 15;
        const int kq  = lane >> 4;
        floatx4 acc = (floatx4)0.f;
        #pragma unroll
        for (int ks = 0; ks < 4; ks++) {
            half8 a = *(const half8*)&rows[m16][ks * 32 + kq * 8];
            half8 b = *(const half8*)&W2T[(wave * 16 + m16) * HIDDEN + ks * 32 + kq * 8];
            acc = __builtin_amdgcn_mfma_f32_16x16x32_f16(a, b, acc, 0, 0, 0);
        }
        const int c = wave * 16 + m16;
        if (c < NCLS) {
            const int gr0 = blockIdx.x * 16 + kq * 4;
            #pragma unroll
            for (int r = 0; r < 4; r++)
                H2s[(long)(gr0 + r) * NCLS + c] = __float2half_rn(acc[r]);
        }
    }
}

// ---------------- Aggregation 2 (+bias) -> fp32 out. 6 nodes x 10 half4-lanes per wave ----------------

__global__ __launch_bounds__(256) void k_agg2(const __half* __restrict__ H2s,
                                              const int* __restrict__ row_ptr,
                                              const int* __restrict__ col,
                                              const float* __restrict__ dinv,
                                              const float* __restrict__ b2,
                                              float* __restrict__ out) {
    const int wave = threadIdx.x >> 6;
    const int lane = threadIdx.x & 63;
    const int g = lane / 10;              // 0..5 active, lanes 60-63 idle
    const int f = lane - g * 10;          // 0..9 -> feats 4f..4f+3
    const int d = blockIdx.x * 24 + wave * 6 + g;
    const bool act = (g < 6) && (d < N_NODES);
    int e0 = 0, e1 = 0;
    if (act) { e0 = row_ptr[d]; e1 = row_ptr[d + 1]; }
    const half4f* base4 = (const half4f*)H2s;   // row stride 10 half4
    float s0 = 0.f, s1 = 0.f, s2 = 0.f, s3 = 0.f;
    int e = e0;
    while (__any(e < e1)) {
        #pragma unroll
        for (int u = 0; u < 8; u++) {     // 8 gathers in flight per group
            if (e + u < e1) {
                half4f v = base4[(long)col[e + u] * 10 + f];
                s0 += (float)v[0]; s1 += (float)v[1]; s2 += (float)v[2]; s3 += (float)v[3];
            }
        }
        e += 8;
    }
    if (act) {
        half4f v = base4[(long)d * 10 + f];   // self-loop (pre-scaled)
        s0 += (float)v[0]; s1 += (float)v[1]; s2 += (float)v[2]; s3 += (float)v[3];
        float dd = dinv[d];
        float4 bbv = ((const float4*)b2)[f];
        float4 o = make_float4(dd * s0 + bbv.x, dd * s1 + bbv.y, dd * s2 + bbv.z, dd * s3 + bbv.w);
        ((float4*)out)[(long)d * 10 + f] = o;
    }
}

// ---------------- launch ----------------

extern "C" void kernel_launch(void* const* d_in, const int* in_sizes, int n_in,
                              void* d_out, int out_size, void* d_ws, size_t ws_size,
                              hipStream_t stream) {
    const float* x  = (const float*)d_in[0];
    const int*   ei = (const int*)d_in[1];
    const float* W1 = (const float*)d_in[2];
    const float* b1 = (const float*)d_in[3];
    const float* W2 = (const float*)d_in[4];
    const float* b2 = (const float*)d_in[5];
    const int* srcE = ei;
    const int* dstE = ei + N_EDGES;

    int*   row_ptr = (int*)d_ws;                    // 100032 ints
    int*   bfill   = row_ptr + 100032;              // 256
    int*   col     = bfill + 256;                   // 1600000
    float* dinv    = (float*)(col + N_EDGES);       // 100032 floats
    __half* H1s    = (__half*)(dinv + 100032);      // 12.8M halfs (25.6 MB)
    __half* H2s    = H1s + (long)N_NODES * HIDDEN;  // 4M halfs (8 MB)
    __half* W1T    = H2s + (long)N_NODES * NCLS;    // 32768 halfs
    __half* W2T    = W1T + IN_DIM * HIDDEN;         // 6144 halfs
    unsigned long long* bpair = (unsigned long long*)(W2T + NCLS_PAD * HIDDEN);  // 2.1M (16.8 MB)

    k_prep   <<<130, 256, 0, stream>>>(W1, W1T, W2, W2T, bfill);
    k_binmm  <<<BIN_BLOCKS + GEMM1_BLOCKS, 256, 0, stream>>>(srcE, dstE, bfill, bpair, x, W1T, H1s);
    k_build  <<<N_BUCKETS, 512, 0, stream>>>(bfill, bpair, row_ptr, dinv, col);
    k_agg1g2 <<<N_NODES / 16, 256, 0, stream>>>(H1s, row_ptr, col, dinv, b1, W2T, H2s);
    k_agg2   <<<(N_NODES + 23) / 24, 256, 0, stream>>>(H2s, row_ptr, col, dinv, b2, (float*)d_out);
}

// Round 9
// 323.698 us; speedup vs baseline: 1.0751x; 1.0162x over previous
//
#include <hip/hip_runtime.h>
#include <hip/hip_bf16.h>
#include <hip/hip_fp16.h>

#define N_NODES 100000
#define N_EDGES 1600000
#define IN_DIM 256
#define HIDDEN 128
#define NCLS 40
#define NCLS_PAD 48      // padded to 3 MFMA n-tiles

#define N_BUCKETS 256
#define NPB 391          // nodes per bucket = ceil(100000/256)
#define BCAP 8192        // bucket capacity (mean 6256, +24 sigma)
#define EPT 16           // edges per thread in bin phase
#define BIN_WG 4096      // edges per workgroup (256*16)
#define BIN_BLOCKS 391   // ceil(N_EDGES / BIN_WG)
#define GEMM1_BLOCKS 782 // ceil(N_NODES / 128)

typedef __attribute__((ext_vector_type(8))) _Float16 half8;
typedef __attribute__((ext_vector_type(4))) _Float16 half4f;
typedef __attribute__((ext_vector_type(4))) float floatx4;

// ---------------- k_prep: W1T / W2T fp16 transposes + bfill zero ----------------

__global__ __launch_bounds__(256) void k_prep(const float* __restrict__ W1, __half* __restrict__ W1T,
                                              const float* __restrict__ W2, __half* __restrict__ W2T,
                                              int* __restrict__ bfill) {
    const int t = threadIdx.x;
    if (blockIdx.x < 128) {              // W1T: [n][k] fp16, 128 x 256
        int i = blockIdx.x * 256 + t;
        int k = i >> 7, n = i & 127;
        W1T[n * IN_DIM + k] = __float2half_rn(W1[i]);
    } else if (blockIdx.x == 128) {      // W2T: [n][k] fp16, 48 x 128, zero-pad n>=40
        for (int i = t; i < NCLS_PAD * HIDDEN; i += 256) {
            int n = i >> 7, k = i & 127;
            W2T[n * HIDDEN + k] = (n < NCLS) ? __float2half_rn(W2[k * NCLS + n]) : __float2half_rn(0.f);
        }
    } else {
        bfill[t] = 0;
    }
}

// ---------------- k_binmm: bin/gemm blocks INTERLEAVED mod 3 (1173 = 3*391) ----------------
// b%3==0 -> bin (391 blocks), else gemm (782 blocks): each CU holds ~1.5 bin + ~3 gemm
// blocks THROUGHOUT the kernel, so bin's VMEM bursts fill gemm's latency stalls (the
// sequential layout only overlapped at the seam). Bin phase: round-3 proven config.
// GEMM phase: B staged in LDS per k-half; A direct per-lane from X with depth-2
// register prefetch (3 rotating buffers, compile-time indices).

__global__ __launch_bounds__(256) void k_binmm(const int* __restrict__ src, const int* __restrict__ dst,
                                               int* __restrict__ bfill,
                                               unsigned long long* __restrict__ bpair,
                                               const float* __restrict__ X,
                                               const __half* __restrict__ W1T,
                                               __half* __restrict__ H1s) {
    __shared__ __align__(16) char smraw[39936];   // union: bin(39936) / gemm1 Bsm(34816)
    const int t = threadIdx.x;
    const int blk = blockIdx.x;

    if (blk % 3 == 0) {
        // ---- bin phase (bin_id = blk/3 in [0,391)) ----
        const int bin_id = blk / 3;
        int* hist   = (int*)smraw;                               // 256
        int* bstart = hist + 256;                                // 256
        int* gbase  = bstart + 256;                              // 256
        unsigned long long* stage = (unsigned long long*)(smraw + 3072);   // 4096 (32 KB)
        unsigned char* bid = (unsigned char*)(smraw + 3072 + 32768);       // 4096
        hist[t] = 0;
        __syncthreads();
        const long e0 = (long)bin_id * BIN_WG;
        const int n_valid = (int)min((long)BIN_WG, (long)N_EDGES - e0);
        int msrc[EPT], mdst[EPT], moff[EPT];
        #pragma unroll
        for (int i = 0; i < EPT; i++) {
            long e = e0 + t + i * 256;
            if (e < N_EDGES) {
                msrc[i] = src[e];
                mdst[i] = dst[e];
                moff[i] = atomicAdd(&hist[mdst[i] / NPB], 1);
            } else {
                mdst[i] = -1;
            }
        }
        __syncthreads();
        if (t < 64) {   // wave 0: exclusive scan of hist[256]
            int carry = 0;
            #pragma unroll
            for (int c = 0; c < 4; c++) {
                int idx = c * 64 + t;
                int hv = hist[idx];
                int s = hv;
                #pragma unroll
                for (int d2 = 1; d2 < 64; d2 <<= 1) {
                    int u = __shfl_up(s, d2, 64);
                    if (t >= d2) s += u;
                }
                bstart[idx] = carry + (s - hv);
                carry += __shfl(s, 63, 64);
            }
        }
        __syncthreads();
        int h = hist[t];
        gbase[t] = (h > 0) ? atomicAdd(&bfill[t], h) : 0;
        #pragma unroll
        for (int i = 0; i < EPT; i++) {
            if (mdst[i] >= 0) {
                int b = mdst[i] / NPB;
                int pos = bstart[b] + moff[i];
                stage[pos] = ((unsigned long long)(unsigned)mdst[i] << 32) | (unsigned)msrc[i];
                bid[pos] = (unsigned char)b;
            }
        }
        __syncthreads();
        for (int i = t; i < n_valid; i += 256) {
            int b = bid[i];
            int dest = gbase[b] + (i - bstart[b]);
            bpair[(long)b * BCAP + dest] = stage[i];
        }
        return;
    }

    // ---- gemm1 phase (gemm_id = blk - blk/3 - 1 in [0,782)) ----
    _Float16 (*Bsm)[136] = (_Float16(*)[136])smraw;   // 128 x 136 fp16 (+8 pad: +4 banks/row)
    const int gemm_id = blk - blk / 3 - 1;
    const int wave = t >> 6;
    const int lane = t & 63;
    const int m16  = lane & 15;
    const int kq   = lane >> 4;
    const int row0 = gemm_id * 128;
    const int arow0 = row0 + wave * 32 + m16;
    const int arow1 = arow0 + 16;
    const bool va0 = arow0 < N_NODES;
    const bool va1 = arow1 < N_NODES;
    const float* pX0 = X + (long)arow0 * IN_DIM + kq * 8;
    const float* pX1 = X + (long)arow1 * IN_DIM + kq * 8;
    const float4 z4 = make_float4(0.f, 0.f, 0.f, 0.f);

    floatx4 acc[2][8];
    #pragma unroll
    for (int mt = 0; mt < 2; mt++)
        #pragma unroll
        for (int i = 0; i < 8; i++) acc[mt][i] = (floatx4)0.f;

    float4 A[3][2][2];   // 3 rotating depth-2 prefetch buffers
    auto loadA3 = [&](int buf, int kbase) {
        if (va0) { A[buf][0][0] = *(const float4*)(pX0 + kbase); A[buf][0][1] = *(const float4*)(pX0 + kbase + 4); }
        else     { A[buf][0][0] = z4; A[buf][0][1] = z4; }
        if (va1) { A[buf][1][0] = *(const float4*)(pX1 + kbase); A[buf][1][1] = *(const float4*)(pX1 + kbase + 4); }
        else     { A[buf][1][0] = z4; A[buf][1][1] = z4; }
    };

    loadA3(0, 0);        // prologue: steps 0 and 1 in flight before B staging
    loadA3(1, 32);

    #pragma unroll
    for (int h = 0; h < 2; h++) {        // two k-halves of 128
        // stage B half h: W1T[n][h*128 .. +128) -> Bsm[n][0..128)
        #pragma unroll
        for (int i = 0; i < 8; i++) {
            int c = t + i * 256;         // 2048 half8-chunks
            int n = c >> 4, k8 = c & 15;
            *(half8*)&Bsm[n][k8 * 8] = *(const half8*)&W1T[n * IN_DIM + h * 128 + k8 * 8];
        }
        __syncthreads();
        #pragma unroll
        for (int s4 = 0; s4 < 4; s4++) { // 4 k-steps of 32 per half
            const int s = h * 4 + s4;    // global step 0..7 (compile-time)
            if (s + 2 < 8) loadA3((s + 2) % 3, (s + 2) * 32);   // depth-2 prefetch
            const float4 (*cA)[2] = A[s % 3];
            half8 a0, a1;
            a0[0] = (_Float16)cA[0][0].x; a0[1] = (_Float16)cA[0][0].y;
            a0[2] = (_Float16)cA[0][0].z; a0[3] = (_Float16)cA[0][0].w;
            a0[4] = (_Float16)cA[0][1].x; a0[5] = (_Float16)cA[0][1].y;
            a0[6] = (_Float16)cA[0][1].z; a0[7] = (_Float16)cA[0][1].w;
            a1[0] = (_Float16)cA[1][0].x; a1[1] = (_Float16)cA[1][0].y;
            a1[2] = (_Float16)cA[1][0].z; a1[3] = (_Float16)cA[1][0].w;
            a1[4] = (_Float16)cA[1][1].x; a1[5] = (_Float16)cA[1][1].y;
            a1[6] = (_Float16)cA[1][1].z; a1[7] = (_Float16)cA[1][1].w;
            const _Float16* bbase = &Bsm[m16][s4 * 32 + kq * 8];
            #pragma unroll
            for (int nt = 0; nt < 8; nt++) {
                half8 b = *(const half8*)(bbase + nt * 16 * 136);
                acc[0][nt] = __builtin_amdgcn_mfma_f32_16x16x32_f16(a0, b, acc[0][nt], 0, 0, 0);
                acc[1][nt] = __builtin_amdgcn_mfma_f32_16x16x32_f16(a1, b, acc[1][nt], 0, 0, 0);
            }
        }
        if (h == 0) __syncthreads();     // all waves done reading Bsm before restage
    }

    #pragma unroll
    for (int mt = 0; mt < 2; mt++) {
        const int gr0 = row0 + wave * 32 + mt * 16 + kq * 4;
        #pragma unroll
        for (int nt = 0; nt < 8; nt++) {
            int c = nt * 16 + m16;
            #pragma unroll
            for (int r = 0; r < 4; r++) {
                if (gr0 + r < N_NODES)
                    H1s[(long)(gr0 + r) * HIDDEN + c] = __float2half_rn(acc[mt][nt][r]);
            }
        }
    }
}

// ---------------- k_build: histogram -> prefix -> row_ptr/dinv -> scatter ----------------
// 512 threads/block (8 waves/CU): TLP for the atomic/gather loops.

__global__ __launch_bounds__(512) void k_build(const int* __restrict__ bfill,
                                               const unsigned long long* __restrict__ bpair,
                                               int* __restrict__ row_ptr, float* __restrict__ dinv,
                                               int* __restrict__ col) {
    __shared__ int h[NPB];
    __shared__ int pfx[NPB];
    __shared__ int sred[8];
    const int b  = blockIdx.x;
    const int nb = b * NPB;
    const int nn = min(NPB, N_NODES - nb);
    const int t  = threadIdx.x;
    int v = (t < b) ? bfill[t] : 0;      // t in [0,512); bfill has 256 entries, b<=255 guards
    #pragma unroll
    for (int dl = 32; dl > 0; dl >>= 1) v += __shfl_down(v, dl, 64);
    if ((t & 63) == 0) sred[t >> 6] = v;
    for (int i = t; i < NPB; i += 512) h[i] = 0;
    __syncthreads();
    int base_b = 0;
    #pragma unroll
    for (int i = 0; i < 8; i++) base_b += sred[i];
    const int n = bfill[b];
    for (int i = t; i < n; i += 512) {
        int dd = (int)(bpair[(long)b * BCAP + i] >> 32);
        atomicAdd(&h[dd - nb], 1);
    }
    __syncthreads();
    if (t < 64) {   // wave 0: exclusive scan of degrees
        int carry = 0;
        #pragma unroll
        for (int c = 0; c < (NPB + 63) / 64; c++) {
            int idx = c * 64 + t;
            int hv = (idx < nn) ? h[idx] : 0;
            int s = hv;
            #pragma unroll
            for (int d2 = 1; d2 < 64; d2 <<= 1) {
                int u = __shfl_up(s, d2, 64);
                if (t >= d2) s += u;
            }
            if (idx < nn) {
                int ex = base_b + carry + (s - hv);
                pfx[idx] = ex;
                row_ptr[nb + idx] = ex;
                dinv[nb + idx] = rsqrtf((float)(hv + 1));   // +1 self-loop
            }
            carry += __shfl(s, 63, 64);
        }
    }
    __syncthreads();
    for (int i = t; i < nn; i += 512) h[i] = 0;   // reuse as fill counters
    __syncthreads();
    for (int i = t; i < n; i += 512) {
        unsigned long long p = bpair[(long)b * BCAP + i];
        int dd = (int)(p >> 32);
        int ss = (int)(p & 0xFFFFFFFFu);
        int pos = pfx[dd - nb] + atomicAdd(&h[dd - nb], 1);
        col[pos] = ss;
    }
    if (b == 0 && t == 0) row_ptr[N_NODES] = N_EDGES;
}

// ---------------- k_agg1g2: Agg1 (+bias+ReLU, pre-scale) + MFMA GEMM2 -> H2s fp16 ----------------
// Block = 16 nodes, each wave serially aggregates 4 nodes with a full-row gather per
// edge (64 lanes x half2 = 256B). e0/e1 forced to SGPR via readfirstlane so col[e..]
// are SGPR scalar loads; therefore dinv[col[e]] are ALSO uniform-address scalar loads
// (SMEM pipe, overlapped with the VMEM gathers) and the sym-norm scale folds into the
// accumulate as fmac-with-SGPR — no separate H1-scale pass anywhere. 8 gathers in flight.

__global__ __launch_bounds__(256) void k_agg1g2(const __half* __restrict__ H1s,
                                                const int* __restrict__ row_ptr,
                                                const int* __restrict__ col,
                                                const float* __restrict__ dinv,
                                                const float* __restrict__ b1,
                                                const __half* __restrict__ W2T,
                                                __half* __restrict__ H2s) {
    __shared__ __align__(16) _Float16 rows[16][136];   // +8 pad: 16B-aligned, 2-way-max banks
    const int wave = threadIdx.x >> 6;
    const int lane = threadIdx.x & 63;
    const __half2* base = (const __half2*)H1s;   // row stride 64 half2
    const float2 bb = ((const float2*)b1)[lane];
    const int d00 = blockIdx.x * 16 + wave * 4;

    #pragma unroll
    for (int i = 0; i < 4; i++) {
        const int d = d00 + i;
        const int e0 = __builtin_amdgcn_readfirstlane(row_ptr[d]);
        const int e1 = __builtin_amdgcn_readfirstlane(row_ptr[d + 1]);
        const float dd = dinv[d];
        float ax = 0.f, ay = 0.f;
        int e = e0;
        for (; e + 7 < e1; e += 8) {
            int s0 = col[e],     s1 = col[e + 1], s2 = col[e + 2], s3 = col[e + 3];
            int s4 = col[e + 4], s5 = col[e + 5], s6 = col[e + 6], s7 = col[e + 7];
            float d0 = dinv[s0], d1 = dinv[s1], d2 = dinv[s2], d3 = dinv[s3];
            float d4 = dinv[s4], d5 = dinv[s5], d6 = dinv[s6], d7 = dinv[s7];
            float2 f0 = __half22float2(base[(long)s0 * 64 + lane]);
            float2 f1 = __half22float2(base[(long)s1 * 64 + lane]);
            float2 f2 = __half22float2(base[(long)s2 * 64 + lane]);
            float2 f3 = __half22float2(base[(long)s3 * 64 + lane]);
            float2 f4 = __half22float2(base[(long)s4 * 64 + lane]);
            float2 f5 = __half22float2(base[(long)s5 * 64 + lane]);
            float2 f6 = __half22float2(base[(long)s6 * 64 + lane]);
            float2 f7 = __half22float2(base[(long)s7 * 64 + lane]);
            ax += d0 * f0.x + d1 * f1.x + d2 * f2.x + d3 * f3.x
                + d4 * f4.x + d5 * f5.x + d6 * f6.x + d7 * f7.x;
            ay += d0 * f0.y + d1 * f1.y + d2 * f2.y + d3 * f3.y
                + d4 * f4.y + d5 * f5.y + d6 * f6.y + d7 * f7.y;
        }
        for (; e + 3 < e1; e += 4) {
            int s0 = col[e], s1 = col[e + 1], s2 = col[e + 2], s3 = col[e + 3];
            float d0 = dinv[s0], d1 = dinv[s1], d2 = dinv[s2], d3 = dinv[s3];
            float2 f0 = __half22float2(base[(long)s0 * 64 + lane]);
            float2 f1 = __half22float2(base[(long)s1 * 64 + lane]);
            float2 f2 = __half22float2(base[(long)s2 * 64 + lane]);
            float2 f3 = __half22float2(base[(long)s3 * 64 + lane]);
            ax += d0 * f0.x + d1 * f1.x + d2 * f2.x + d3 * f3.x;
            ay += d0 * f0.y + d1 * f1.y + d2 * f2.y + d3 * f3.y;
        }
        for (; e < e1; e++) {
            int s = col[e];
            float dv = dinv[s];
            float2 f = __half22float2(base[(long)s * 64 + lane]);
            ax += dv * f.x; ay += dv * f.y;
        }
        // self-loop (unscaled H1 row x dd)
        float2 fs = __half22float2(base[(long)d * 64 + lane]);
        ax += dd * fs.x; ay += dd * fs.y;
        // bias + relu, then pre-scale by dd so the layer-2 MFMA needs no post-scale
        float ox = fmaxf(dd * ax + bb.x, 0.f) * dd;
        float oy = fmaxf(dd * ay + bb.y, 0.f) * dd;
        *(__half2*)&rows[wave * 4 + i][lane * 2] =
            __halves2half2(__float2half_rn(ox), __float2half_rn(oy));
    }
    __syncthreads();

    if (wave < 3) {   // 3 n-tiles of 16 cols (48 padded, 40 real)
        const int m16 = lane & 15;
        const int kq  = lane >> 4;
        floatx4 acc = (floatx4)0.f;
        #pragma unroll
        for (int ks = 0; ks < 4; ks++) {
            half8 a = *(const half8*)&rows[m16][ks * 32 + kq * 8];
            half8 b = *(const half8*)&W2T[(wave * 16 + m16) * HIDDEN + ks * 32 + kq * 8];
            acc = __builtin_amdgcn_mfma_f32_16x16x32_f16(a, b, acc, 0, 0, 0);
        }
        const int c = wave * 16 + m16;
        if (c < NCLS) {
            const int gr0 = blockIdx.x * 16 + kq * 4;
            #pragma unroll
            for (int r = 0; r < 4; r++)
                H2s[(long)(gr0 + r) * NCLS + c] = __float2half_rn(acc[r]);
        }
    }
}

// ---------------- Aggregation 2 (+bias) -> fp32 out. 12 nodes x 5 half8-lanes per wave ----------------
// (was 6 nodes x 10 half4-lanes: 16B loads halve per-edge instruction count; rows are
// 80B = 5x16B so every H2s row is 16B-aligned; lanes 60-63 idle)

__global__ __launch_bounds__(256) void k_agg2(const __half* __restrict__ H2s,
                                              const int* __restrict__ row_ptr,
                                              const int* __restrict__ col,
                                              const float* __restrict__ dinv,
                                              const float* __restrict__ b2,
                                              float* __restrict__ out) {
    const int wave = threadIdx.x >> 6;
    const int lane = threadIdx.x & 63;
    const int g = lane / 5;               // 0..11 active, lanes 60-63 idle
    const int f = lane - g * 5;           // 0..4 -> feats 8f..8f+7
    const int d = blockIdx.x * 48 + wave * 12 + g;
    const bool act = (g < 12) && (d < N_NODES);
    int e0 = 0, e1 = 0;
    if (act) { e0 = row_ptr[d]; e1 = row_ptr[d + 1]; }
    const half8* base8 = (const half8*)H2s;   // row stride 5 half8
    float s0 = 0.f, s1 = 0.f, s2 = 0.f, s3 = 0.f, s4 = 0.f, s5 = 0.f, s6 = 0.f, s7 = 0.f;
    int e = e0;
    while (__any(e < e1)) {
        #pragma unroll
        for (int u = 0; u < 8; u++) {     // 8 gathers in flight per group
            if (e + u < e1) {
                half8 v = base8[(long)col[e + u] * 5 + f];
                s0 += (float)v[0]; s1 += (float)v[1]; s2 += (float)v[2]; s3 += (float)v[3];
                s4 += (float)v[4]; s5 += (float)v[5]; s6 += (float)v[6]; s7 += (float)v[7];
            }
        }
        e += 8;
    }
    if (act) {
        half8 v = base8[(long)d * 5 + f];   // self-loop (pre-scaled)
        s0 += (float)v[0]; s1 += (float)v[1]; s2 += (float)v[2]; s3 += (float)v[3];
        s4 += (float)v[4]; s5 += (float)v[5]; s6 += (float)v[6]; s7 += (float)v[7];
        float dd = dinv[d];
        float4 bb0 = ((const float4*)b2)[f * 2];
        float4 bb1 = ((const float4*)b2)[f * 2 + 1];
        float4 o0 = make_float4(dd * s0 + bb0.x, dd * s1 + bb0.y, dd * s2 + bb0.z, dd * s3 + bb0.w);
        float4 o1 = make_float4(dd * s4 + bb1.x, dd * s5 + bb1.y, dd * s6 + bb1.z, dd * s7 + bb1.w);
        ((float4*)out)[(long)d * 10 + f * 2]     = o0;
        ((float4*)out)[(long)d * 10 + f * 2 + 1] = o1;
    }
}

// ---------------- launch ----------------

extern "C" void kernel_launch(void* const* d_in, const int* in_sizes, int n_in,
                              void* d_out, int out_size, void* d_ws, size_t ws_size,
                              hipStream_t stream) {
    const float* x  = (const float*)d_in[0];
    const int*   ei = (const int*)d_in[1];
    const float* W1 = (const float*)d_in[2];
    const float* b1 = (const float*)d_in[3];
    const float* W2 = (const float*)d_in[4];
    const float* b2 = (const float*)d_in[5];
    const int* srcE = ei;
    const int* dstE = ei + N_EDGES;

    int*   row_ptr = (int*)d_ws;                    // 100032 ints
    int*   bfill   = row_ptr + 100032;              // 256
    int*   col     = bfill + 256;                   // 1600000
    float* dinv    = (float*)(col + N_EDGES);       // 100032 floats
    __half* H1s    = (__half*)(dinv + 100032);      // 12.8M halfs (25.6 MB)
    __half* H2s    = H1s + (long)N_NODES * HIDDEN;  // 4M halfs (8 MB)
    __half* W1T    = H2s + (long)N_NODES * NCLS;    // 32768 halfs
    __half* W2T    = W1T + IN_DIM * HIDDEN;         // 6144 halfs
    unsigned long long* bpair = (unsigned long long*)(W2T + NCLS_PAD * HIDDEN);  // 2.1M (16.8 MB)

    k_prep   <<<130, 256, 0, stream>>>(W1, W1T, W2, W2T, bfill);
    k_binmm  <<<BIN_BLOCKS + GEMM1_BLOCKS, 256, 0, stream>>>(srcE, dstE, bfill, bpair, x, W1T, H1s);
    k_build  <<<N_BUCKETS, 512, 0, stream>>>(bfill, bpair, row_ptr, dinv, col);
    k_agg1g2 <<<N_NODES / 16, 256, 0, stream>>>(H1s, row_ptr, col, dinv, b1, W2T, H2s);
    k_agg2   <<<(N_NODES + 47) / 48, 256, 0, stream>>>(H2s, row_ptr, col, dinv, b2, (float*)d_out);
}